// Round 2
// baseline (544.609 us; speedup 1.0000x reference)
//
#include <hip/hip_runtime.h>
#include <hip/hip_bf16.h>
#include <cstdint>

// Problem constants
#define Ln 2048
#define Bn 64
#define Kd 256
#define Vd 256
#define Hn 8

#define CH 64    // l-rows per fused chunk
#define NCH 32   // number of chunks (Ln / CH)

using u32 = unsigned int;
using u16 = unsigned short;

__device__ __forceinline__ float bflo(u32 u) { return __uint_as_float(u << 16); }
__device__ __forceinline__ float bfhi(u32 u) { return __uint_as_float(u & 0xffff0000u); }
__device__ __forceinline__ float bf1(u16 s) { return __uint_as_float(((u32)s) << 16); }

// Device-side dtype sniff on `keys` (little-endian aware): u16[2i] is the LOW
// mantissa half of float[i] for fp32 data -> ~14% sane-bf16; for genuine bf16
// data it's a real N(0,1) value -> ~100% sane. (Rounds 1-3 verified: fp32.)
__device__ __forceinline__ bool sniff_bf16(const void* keys) {
  const u16* q = (const u16*)keys;
  int lane = threadIdx.x & 63;
  u16 u = q[2 * (lane * 127)];
  u32 e = (u >> 7) & 0xff;
  bool sane = (u == 0) || (e >= 100 && e <= 134);
  return __popcll(__ballot(sane)) > 32;
}

// ---------------------------------------------------------------------------
// k_prep: q = query @ Wq + bq  (fp32 in ws)   grid (4 chunks, 64 b), block 256
__global__ __launch_bounds__(256) void k_prep(const void* keys, const void* query,
                                              const void* Wq, const void* bq,
                                              float* q_ws) {
  const bool bf = sniff_bf16(keys);
  const int t = threadIdx.x;
  const int chunk = blockIdx.x;  // 0..3
  const int b = blockIdx.y;      // 0..63

  __shared__ float ql[256];
  ql[t] = bf ? bf1(((const u16*)query)[b * 256 + t]) : ((const float*)query)[b * 256 + t];
  __syncthreads();

  int c0 = chunk * 512 + 2 * t;  // two output columns per thread
  float a0, a1;
  if (bf) { a0 = bf1(((const u16*)bq)[c0]); a1 = bf1(((const u16*)bq)[c0 + 1]); }
  else    { a0 = ((const float*)bq)[c0];    a1 = ((const float*)bq)[c0 + 1]; }

  if (bf) {
    const u32* w = (const u32*)Wq + chunk * 256 + t;
    for (int k0 = 0; k0 < 256; k0 += 16) {
      u32 wv[16];
#pragma unroll
      for (int j = 0; j < 16; j++) wv[j] = w[(size_t)(k0 + j) * 1024];
#pragma unroll
      for (int j = 0; j < 16; j++) {
        float qk = ql[k0 + j];
        a0 += qk * bflo(wv[j]); a1 += qk * bfhi(wv[j]);
      }
    }
  } else {
    const float2* w = (const float2*)Wq + chunk * 256 + t;
    for (int k0 = 0; k0 < 256; k0 += 16) {
      float2 wv[16];
#pragma unroll
      for (int j = 0; j < 16; j++) wv[j] = w[(size_t)(k0 + j) * 1024];
#pragma unroll
      for (int j = 0; j < 16; j++) {
        float qk = ql[k0 + j];
        a0 += qk * wv[j].x; a1 += qk * wv[j].y;
      }
    }
  }
  q_ws[b * 2048 + c0] = a0;
  q_ws[b * 2048 + c0 + 1] = a1;
}

// ---------------------------------------------------------------------------
// k_fused: per (chunk of 64 l, b): scores with q in REGISTERS (lane=(h,kslice),
// keys via LDS broadcast, 8-lane shuffle reduce), partial softmax, weighted
// vals sum with in-wave combine. grid (32, 64), block 256.
// Register budget: score peak ~95 (qreg 32 + accs 16 + stage 32 + addr),
// read peak ~80 -> fits the 128-VGPR cap of (256,4) with NO spills.
__global__ __launch_bounds__(256, 4) void k_fused(const void* keys, const void* vals,
                                                  const void* rpe, const int* steps,
                                                  const float* q_ws, float* O_part,
                                                  float2* mz_part) {
  const int b = blockIdx.y, chunk = blockIdx.x;
  const int lstart = chunk * CH;
  const int stepb = steps[b];
  if (lstart >= stepb) return;  // dead chunk
  const int lcnt = min(CH, stepb - lstart);
  const bool bf = sniff_bf16(keys);
  const int t = threadIdx.x;
  const int lane = t & 63;
  const int wave = __builtin_amdgcn_readfirstlane(t >> 6);  // 0..3

  __shared__ __align__(16) float ks[CH * 132];   // 33.8 KB (one 128-k half)
  __shared__ __align__(16) float w_lds[CH * 12]; // scores -> weights
  __shared__ float rpe_lds[CH];
  __shared__ float2 mz_lds[8];

  // rpe staging (one dword per row; L2-shared across b)
  if (t < CH) {
    int l = lstart + t;
    rpe_lds[t] = bf ? bf1(((const u16*)rpe)[l * 64 + b]) : ((const float*)rpe)[l * 64 + b];
  }

  // ---- q into registers: lane = (h8, ks8); slice k = j*32 + ks8*4, j=0..7 ----
  const int h8 = lane >> 3, ks8 = lane & 7;
  float4 qreg[8];
  {
    const float* qb = q_ws + b * 2048 + h8 * 256 + ks8 * 4;
#pragma unroll
    for (int j = 0; j < 8; j++) qreg[j] = *(const float4*)&qb[j * 32];
  }

  // ================= score phase =================
  float accs[16];
#pragma unroll
  for (int r = 0; r < 16; r++) accs[r] = 0.f;

  auto COMPUTE = [&](int kh2) {
    const int rowbase = wave * 16;
    const float4 q0 = qreg[kh2 * 4 + 0], q1 = qreg[kh2 * 4 + 1];
    const float4 q2 = qreg[kh2 * 4 + 2], q3 = qreg[kh2 * 4 + 3];
#pragma unroll
    for (int r = 0; r < 16; r++) {
      const float* kp = &ks[(rowbase + r) * 132 + ks8 * 4];
      float4 k0 = *(const float4*)kp;
      float4 k1 = *(const float4*)(kp + 32);
      float4 k2 = *(const float4*)(kp + 64);
      float4 k3 = *(const float4*)(kp + 96);
      float a = accs[r];
      a += k0.x * q0.x + k0.y * q0.y + k0.z * q0.z + k0.w * q0.w;
      a += k1.x * q1.x + k1.y * q1.y + k1.z * q1.z + k1.w * q1.w;
      a += k2.x * q2.x + k2.y * q2.y + k2.z * q2.z + k2.w * q2.w;
      a += k3.x * q3.x + k3.y * q3.y + k3.z * q3.z + k3.w * q3.w;
      accs[r] = a;
    }
  };

  for (int kh = 0; kh < 2; kh++) {
    if (kh) __syncthreads();  // protect ks reuse across halves
    if (bf) {
      const int c = t & 15, r0 = t >> 4;  // 16 uint4 per row-half, 16 row-groups
      const u16* srcb = (const u16*)keys + ((size_t)(lstart + r0) * 64 + b) * 256 + kh * 128;
      uint4 uu[4];
#pragma unroll
      for (int rr = 0; rr < 4; rr++)
        uu[rr] = *((const uint4*)(srcb + (size_t)rr * 16 * 16384) + c);
#pragma unroll
      for (int rr = 0; rr < 4; rr++) {
        int row = r0 + rr * 16;
        float* dst = &ks[row * 132 + c * 8];
        float4 lo, hi;
        lo.x = bflo(uu[rr].x); lo.y = bfhi(uu[rr].x); lo.z = bflo(uu[rr].y); lo.w = bfhi(uu[rr].y);
        hi.x = bflo(uu[rr].z); hi.y = bfhi(uu[rr].z); hi.z = bflo(uu[rr].w); hi.w = bfhi(uu[rr].w);
        *(float4*)dst = lo;
        *(float4*)(dst + 4) = hi;
      }
    } else {
      const int c = t & 31, r0 = t >> 5;  // 32 float4 per row-half, 8 row-groups
      const float* src = (const float*)keys + ((size_t)(lstart + r0) * 64 + b) * 256 + kh * 128 + c * 4;
      float4 vv[8];
#pragma unroll
      for (int rr = 0; rr < 8; rr++) vv[rr] = *(const float4*)(src + (size_t)rr * 8 * 16384);
#pragma unroll
      for (int rr = 0; rr < 8; rr++) *(float4*)&ks[(r0 + rr * 8) * 132 + c * 4] = vv[rr];
    }
    __syncthreads();
    COMPUTE(kh);
  }

  // reduce over 8-lane k-slice groups; write scores * rpe (per-wave rows -> no race)
  {
    const int rowbase = wave * 16;
#pragma unroll
    for (int r = 0; r < 16; r++) {
      float v = accs[r];
      v += __shfl_xor(v, 1);
      v += __shfl_xor(v, 2);
      v += __shfl_xor(v, 4);
      if (ks8 == 0) w_lds[(rowbase + r) * 12 + h8] = v * rpe_lds[rowbase + r];
    }
  }
  __syncthreads();

  // ================= partial softmax: 32 threads per h over 64 rows ==========
  {
    const int h = t >> 5, j = t & 31;
    float s0 = (j < lcnt) ? w_lds[j * 12 + h] : -3.0e38f;
    float s1 = (j + 32 < lcnt) ? w_lds[(j + 32) * 12 + h] : -3.0e38f;
    float m = fmaxf(s0, s1);
#pragma unroll
    for (int off = 16; off >= 1; off >>= 1) m = fmaxf(m, __shfl_xor(m, off, 32));
    float e0 = (j < lcnt) ? __expf(s0 - m) : 0.f;
    float e1 = (j + 32 < lcnt) ? __expf(s1 - m) : 0.f;
    w_lds[j * 12 + h] = e0;          // dead rows get 0
    w_lds[(j + 32) * 12 + h] = e1;
    float zs = e0 + e1;
#pragma unroll
    for (int off = 16; off >= 1; off >>= 1) zs += __shfl_xor(zs, off, 32);
    if (j == 0) mz_lds[h] = make_float2(m, zs);
  }
  __syncthreads();
  if (t < 8) mz_part[((size_t)chunk * 64 + b) * 8 + t] = mz_lds[t];

  // ================= read phase: O_c[h][v] = sum_l w[l][h]*vals[l][v] ========
  // wave owns v-slice [wave*64, wave*64+64); lane = (rg = lane>>4, vslot = lane&15)
  const int vslot = lane & 15, rg = lane >> 4;
  float acc[8][4];
#pragma unroll
  for (int hh = 0; hh < 8; hh++)
#pragma unroll
    for (int cc = 0; cc < 4; cc++) acc[hh][cc] = 0.f;

  if (bf) {
    const u32* vb = (const u32*)vals + ((size_t)lstart * 64 + b) * 128 + wave * 32 + vslot * 2;
    for (int i0 = 0; i0 < 16; i0 += 8) {
      uint2 uu[8];
#pragma unroll
      for (int jb = 0; jb < 8; jb++) {
        int row = rg + 4 * (i0 + jb);
        uu[jb] = *(const uint2*)(vb + (size_t)row * 8192);
      }
#pragma unroll
      for (int jb = 0; jb < 8; jb++) {
        int row = rg + 4 * (i0 + jb);
        float4 w0 = *(const float4*)&w_lds[row * 12];
        float4 w1 = *(const float4*)&w_lds[row * 12 + 4];
        float v0 = bflo(uu[jb].x), v1 = bfhi(uu[jb].x);
        float v2 = bflo(uu[jb].y), v3 = bfhi(uu[jb].y);
        acc[0][0] += w0.x * v0; acc[0][1] += w0.x * v1; acc[0][2] += w0.x * v2; acc[0][3] += w0.x * v3;
        acc[1][0] += w0.y * v0; acc[1][1] += w0.y * v1; acc[1][2] += w0.y * v2; acc[1][3] += w0.y * v3;
        acc[2][0] += w0.z * v0; acc[2][1] += w0.z * v1; acc[2][2] += w0.z * v2; acc[2][3] += w0.z * v3;
        acc[3][0] += w0.w * v0; acc[3][1] += w0.w * v1; acc[3][2] += w0.w * v2; acc[3][3] += w0.w * v3;
        acc[4][0] += w1.x * v0; acc[4][1] += w1.x * v1; acc[4][2] += w1.x * v2; acc[4][3] += w1.x * v3;
        acc[5][0] += w1.y * v0; acc[5][1] += w1.y * v1; acc[5][2] += w1.y * v2; acc[5][3] += w1.y * v3;
        acc[6][0] += w1.z * v0; acc[6][1] += w1.z * v1; acc[6][2] += w1.z * v2; acc[6][3] += w1.z * v3;
        acc[7][0] += w1.w * v0; acc[7][1] += w1.w * v1; acc[7][2] += w1.w * v2; acc[7][3] += w1.w * v3;
      }
    }
  } else {
    const float* vb = (const float*)vals + ((size_t)lstart * 64 + b) * 256 + wave * 64 + vslot * 4;
    for (int i0 = 0; i0 < 16; i0 += 8) {
      float4 vv[8];
#pragma unroll
      for (int jb = 0; jb < 8; jb++) {
        int row = rg + 4 * (i0 + jb);
        vv[jb] = *(const float4*)(vb + (size_t)row * 16384);
      }
#pragma unroll
      for (int jb = 0; jb < 8; jb++) {
        int row = rg + 4 * (i0 + jb);
        float4 w0 = *(const float4*)&w_lds[row * 12];
        float4 w1 = *(const float4*)&w_lds[row * 12 + 4];
        acc[0][0] += w0.x * vv[jb].x; acc[0][1] += w0.x * vv[jb].y; acc[0][2] += w0.x * vv[jb].z; acc[0][3] += w0.x * vv[jb].w;
        acc[1][0] += w0.y * vv[jb].x; acc[1][1] += w0.y * vv[jb].y; acc[1][2] += w0.y * vv[jb].z; acc[1][3] += w0.y * vv[jb].w;
        acc[2][0] += w0.z * vv[jb].x; acc[2][1] += w0.z * vv[jb].y; acc[2][2] += w0.z * vv[jb].z; acc[2][3] += w0.z * vv[jb].w;
        acc[3][0] += w0.w * vv[jb].x; acc[3][1] += w0.w * vv[jb].y; acc[3][2] += w0.w * vv[jb].z; acc[3][3] += w0.w * vv[jb].w;
        acc[4][0] += w1.x * vv[jb].x; acc[4][1] += w1.x * vv[jb].y; acc[4][2] += w1.x * vv[jb].z; acc[4][3] += w1.x * vv[jb].w;
        acc[5][0] += w1.y * vv[jb].x; acc[5][1] += w1.y * vv[jb].y; acc[5][2] += w1.y * vv[jb].z; acc[5][3] += w1.y * vv[jb].w;
        acc[6][0] += w1.z * vv[jb].x; acc[6][1] += w1.z * vv[jb].y; acc[6][2] += w1.z * vv[jb].z; acc[6][3] += w1.z * vv[jb].w;
        acc[7][0] += w1.w * vv[jb].x; acc[7][1] += w1.w * vv[jb].y; acc[7][2] += w1.w * vv[jb].z; acc[7][3] += w1.w * vv[jb].w;
      }
    }
  }

  // in-wave combine over 4 row-groups, then 16 lanes store the wave's v-slice
#pragma unroll
  for (int hh = 0; hh < 8; hh++)
#pragma unroll
    for (int cc = 0; cc < 4; cc++) {
      float v = acc[hh][cc];
      v += __shfl_xor(v, 16);
      v += __shfl_xor(v, 32);
      acc[hh][cc] = v;
    }
  if (rg == 0) {
    float* op = O_part + ((size_t)chunk * 64 + b) * 2048 + wave * 64 + vslot * 4;
#pragma unroll
    for (int hh = 0; hh < 8; hh++) {
      float4 o = make_float4(acc[hh][0], acc[hh][1], acc[hh][2], acc[hh][3]);
      *(float4*)&op[hh * 256] = o;
    }
  }
}

// ---------------------------------------------------------------------------
// k_out1: per (h,b): combine 32 chunk partials -> rn[256]; out_part = rn @ Wa
// grid (8 h, 64 b), block 256 (one output column each). Batched loads.
__global__ __launch_bounds__(256) void k_out1(const void* keys, const void* Wa,
                                              const int* steps, const float* O_part,
                                              const float2* mz_part, float* out_part) {
  const int h = blockIdx.x, b = blockIdx.y;
  const bool bf = sniff_bf16(keys);
  const int t = threadIdx.x;  // 0..255 = output column
  const int nlive = (steps[b] + CH - 1) >> 6;  // 1..32

  // chunk scale factors (uniform scalar work, all threads redundant)
  float2 mzv[NCH];
#pragma unroll
  for (int c = 0; c < NCH; c++)
    mzv[c] = (c < nlive) ? mz_part[((size_t)c * 64 + b) * 8 + h] : make_float2(-3.0e38f, 0.f);
  float M = -3.0e38f;
#pragma unroll
  for (int c = 0; c < NCH; c++) M = fmaxf(M, mzv[c].x);
  float sc[NCH];
  float Z = 0.f;
#pragma unroll
  for (int c = 0; c < NCH; c++) {
    sc[c] = __expf(mzv[c].x - M);
    Z += sc[c] * mzv[c].y;
  }
  const float zi = 1.0f / Z;

  // combine O_part chunks (two batches of 16 independent loads)
  __shared__ float rn[256];
  {
    const float* op = O_part + (size_t)b * 2048 + h * 256 + t;
    float s = 0.f;
    float ov[16];
#pragma unroll
    for (int c = 0; c < 16; c++) ov[c] = (c < nlive) ? op[(size_t)c * 131072] : 0.f;
#pragma unroll
    for (int c = 0; c < 16; c++) s += sc[c] * ov[c];
#pragma unroll
    for (int c = 0; c < 16; c++) ov[c] = (c + 16 < nlive) ? op[(size_t)(c + 16) * 131072] : 0.f;
#pragma unroll
    for (int c = 0; c < 16; c++) s += sc[c + 16] * ov[c];
    rn[t] = s * zi;
  }
  __syncthreads();

  float a = 0.f;
  if (bf) {
    const u32* wa = (const u32*)Wa + (size_t)(h * 256) * 128 + (t >> 1);
    const bool hi = (t & 1);
    for (int c0 = 0; c0 < 256; c0 += 16) {
      u32 wv[16];
#pragma unroll
      for (int j = 0; j < 16; j++) wv[j] = wa[(size_t)(c0 + j) * 128];
#pragma unroll
      for (int j = 0; j < 16; j++)
        a += rn[c0 + j] * (hi ? bfhi(wv[j]) : bflo(wv[j]));
    }
  } else {
    const float* wa = (const float*)Wa + (size_t)(h * 256) * 256 + t;
    for (int c0 = 0; c0 < 256; c0 += 16) {
      float wv[16];
#pragma unroll
      for (int j = 0; j < 16; j++) wv[j] = wa[(size_t)(c0 + j) * 256];
#pragma unroll
      for (int j = 0; j < 16; j++) a += rn[c0 + j] * wv[j];
    }
  }
  out_part[(size_t)(h * 64 + b) * 256 + t] = a;
}

// ---------------------------------------------------------------------------
// k_out2: out[b,v] = sum_h out_part[h][b][v] + ba[v]   (dtype by sniff)
// grid 64, block 256
__global__ __launch_bounds__(256) void k_out2(const void* keys, const void* ba,
                                              const float* out_part, void* out) {
  const int b = blockIdx.x, t = threadIdx.x;
  const bool bf = sniff_bf16(keys);
  float s = bf ? bf1(((const u16*)ba)[t]) : ((const float*)ba)[t];
  float ov[8];
#pragma unroll
  for (int h = 0; h < 8; h++) ov[h] = out_part[(size_t)(h * 64 + b) * 256 + t];
#pragma unroll
  for (int h = 0; h < 8; h++) s += ov[h];
  if (bf)
    ((__hip_bfloat16*)out)[b * 256 + t] = __float2bfloat16(s);
  else
    ((float*)out)[b * 256 + t] = s;
}

// ---------------------------------------------------------------------------
extern "C" void kernel_launch(void* const* d_in, const int* in_sizes, int n_in,
                              void* d_out, int out_size, void* d_ws, size_t ws_size,
                              hipStream_t stream) {
  (void)in_sizes; (void)n_in; (void)out_size; (void)ws_size;
  const void* query = d_in[0];
  const void* keys = d_in[1];
  const void* vals = d_in[2];
  const void* rpe = d_in[3];
  const void* Wq = d_in[4];
  const void* bq = d_in[5];
  const void* Wa = d_in[6];
  const void* ba = d_in[7];
  const int* steps = (const int*)d_in[8];

  float* ws = (float*)d_ws;
  float* q_ws = ws;                                  // 131072 f
  float* O_part = ws + 131072;                       // 4194304 f (32 chunks x 64 b x 2048)
  float2* mz_part = (float2*)(ws + 131072 + 4194304);  // 32768 f
  float* out_part = ws + 131072 + 4194304 + 32768;   // 131072 f  (total ~18 MB)

  k_prep<<<dim3(4, 64), 256, 0, stream>>>(keys, query, Wq, bq, q_ws);
  k_fused<<<dim3(NCH, 64), 256, 0, stream>>>(keys, vals, rpe, steps, q_ws, O_part, mz_part);
  k_out1<<<dim3(8, 64), 256, 0, stream>>>(keys, Wa, steps, O_part, mz_part, out_part);
  k_out2<<<64, 256, 0, stream>>>(keys, ba, out_part, d_out);
}

// Round 3
// 318.697 us; speedup vs baseline: 1.7089x; 1.7089x over previous
//
#include <hip/hip_runtime.h>
#include <hip/hip_bf16.h>
#include <cstdint>

// Problem constants
#define Ln 2048
#define Bn 64
#define Kd 256
#define Vd 256
#define Hn 8

#define CH 64    // l-rows per fused chunk
#define NCH 32   // number of chunks (Ln / CH)

using u32 = unsigned int;
using u16 = unsigned short;

__device__ __forceinline__ float bflo(u32 u) { return __uint_as_float(u << 16); }
__device__ __forceinline__ float bfhi(u32 u) { return __uint_as_float(u & 0xffff0000u); }
__device__ __forceinline__ float bf1(u16 s) { return __uint_as_float(((u32)s) << 16); }

// Device-side dtype sniff on `keys` (little-endian aware): u16[2i] is the LOW
// mantissa half of float[i] for fp32 data -> ~14% sane-bf16; for genuine bf16
// data it's a real N(0,1) value -> ~100% sane. (Rounds 1-3 verified: fp32.)
__device__ __forceinline__ bool sniff_bf16(const void* keys) {
  const u16* q = (const u16*)keys;
  int lane = threadIdx.x & 63;
  u16 u = q[2 * (lane * 127)];
  u32 e = (u >> 7) & 0xff;
  bool sane = (u == 0) || (e >= 100 && e <= 134);
  return __popcll(__ballot(sane)) > 32;
}

// ---------------------------------------------------------------------------
// k_prep: q = query @ Wq + bq  (fp32 in ws)   grid (4 chunks, 64 b), block 256
__global__ __launch_bounds__(256) void k_prep(const void* keys, const void* query,
                                              const void* Wq, const void* bq,
                                              float* q_ws) {
  const bool bf = sniff_bf16(keys);
  const int t = threadIdx.x;
  const int chunk = blockIdx.x;  // 0..3
  const int b = blockIdx.y;      // 0..63

  __shared__ float ql[256];
  ql[t] = bf ? bf1(((const u16*)query)[b * 256 + t]) : ((const float*)query)[b * 256 + t];
  __syncthreads();

  int c0 = chunk * 512 + 2 * t;  // two output columns per thread
  float a0, a1;
  if (bf) { a0 = bf1(((const u16*)bq)[c0]); a1 = bf1(((const u16*)bq)[c0 + 1]); }
  else    { a0 = ((const float*)bq)[c0];    a1 = ((const float*)bq)[c0 + 1]; }

  if (bf) {
    const u32* w = (const u32*)Wq + chunk * 256 + t;
    for (int k0 = 0; k0 < 256; k0 += 16) {
      u32 wv[16];
#pragma unroll
      for (int j = 0; j < 16; j++) wv[j] = w[(size_t)(k0 + j) * 1024];
#pragma unroll
      for (int j = 0; j < 16; j++) {
        float qk = ql[k0 + j];
        a0 += qk * bflo(wv[j]); a1 += qk * bfhi(wv[j]);
      }
    }
  } else {
    const float2* w = (const float2*)Wq + chunk * 256 + t;
    for (int k0 = 0; k0 < 256; k0 += 16) {
      float2 wv[16];
#pragma unroll
      for (int j = 0; j < 16; j++) wv[j] = w[(size_t)(k0 + j) * 1024];
#pragma unroll
      for (int j = 0; j < 16; j++) {
        float qk = ql[k0 + j];
        a0 += qk * wv[j].x; a1 += qk * wv[j].y;
      }
    }
  }
  q_ws[b * 2048 + c0] = a0;
  q_ws[b * 2048 + c0 + 1] = a1;
}

// ---------------------------------------------------------------------------
// k_fused: per (chunk of 64 l, b): scores with q in REGISTERS (lane=(h,kslice),
// keys via LDS broadcast, 8-lane shuffle reduce), partial softmax, weighted
// vals sum with in-wave combine. grid (32, 64), block 256.
// NOTE: plain __launch_bounds__(256) — adding a min-waves arg (",4") made the
// backend clamp to 64 VGPRs and spill ~100 VGPRs of live state to scratch
// (rounds 1-2: WRITE_SIZE 79->393 MB). Round 0 allocated 120 VGPRs spill-free.
// All COMPUTE/stage calls use literal constants so qreg indexing is
// compile-time (runtime-indexed reg arrays demote to scratch, rule #20).
__global__ __launch_bounds__(256) void k_fused(const void* keys, const void* vals,
                                               const void* rpe, const int* steps,
                                               const float* q_ws, float* O_part,
                                               float2* mz_part) {
  const int b = blockIdx.y, chunk = blockIdx.x;
  const int lstart = chunk * CH;
  const int stepb = steps[b];
  if (lstart >= stepb) return;  // dead chunk
  const int lcnt = min(CH, stepb - lstart);
  const bool bf = sniff_bf16(keys);
  const int t = threadIdx.x;
  const int lane = t & 63;
  const int wave = __builtin_amdgcn_readfirstlane(t >> 6);  // 0..3

  __shared__ __align__(16) float ks[CH * 132];   // 33.8 KB (one 128-k half)
  __shared__ __align__(16) float w_lds[CH * 12]; // scores -> weights
  __shared__ float rpe_lds[CH];
  __shared__ float2 mz_lds[8];

  // rpe staging (one dword per row; L2-shared across b)
  if (t < CH) {
    int l = lstart + t;
    rpe_lds[t] = bf ? bf1(((const u16*)rpe)[l * 64 + b]) : ((const float*)rpe)[l * 64 + b];
  }

  // ---- q into registers: lane = (h8, ks8); slice k = j*32 + ks8*4, j=0..7 ----
  const int h8 = lane >> 3, ks8 = lane & 7;
  float4 qreg[8];
  {
    const float* qb = q_ws + b * 2048 + h8 * 256 + ks8 * 4;
#pragma unroll
    for (int j = 0; j < 8; j++) qreg[j] = *(const float4*)&qb[j * 32];
  }

  // ================= score phase =================
  float accs[16];
#pragma unroll
  for (int r = 0; r < 16; r++) accs[r] = 0.f;

  auto COMPUTE = [&](int kh2) {
    const int rowbase = wave * 16;
    const float4 q0 = qreg[kh2 * 4 + 0], q1 = qreg[kh2 * 4 + 1];
    const float4 q2 = qreg[kh2 * 4 + 2], q3 = qreg[kh2 * 4 + 3];
#pragma unroll
    for (int r = 0; r < 16; r++) {
      const float* kp = &ks[(rowbase + r) * 132 + ks8 * 4];
      float4 k0 = *(const float4*)kp;
      float4 k1 = *(const float4*)(kp + 32);
      float4 k2 = *(const float4*)(kp + 64);
      float4 k3 = *(const float4*)(kp + 96);
      float a = accs[r];
      a += k0.x * q0.x + k0.y * q0.y + k0.z * q0.z + k0.w * q0.w;
      a += k1.x * q1.x + k1.y * q1.y + k1.z * q1.z + k1.w * q1.w;
      a += k2.x * q2.x + k2.y * q2.y + k2.z * q2.z + k2.w * q2.w;
      a += k3.x * q3.x + k3.y * q3.y + k3.z * q3.z + k3.w * q3.w;
      accs[r] = a;
    }
  };

  if (bf) {
    const int c = t & 15, r0 = t >> 4;  // 16 uint4 per row-half, 16 row-groups
    auto LOADB = [&](int kh2, uint4* uu) {
      const u16* srcb = (const u16*)keys + ((size_t)(lstart + r0) * 64 + b) * 256 + kh2 * 128;
#pragma unroll
      for (int rr = 0; rr < 4; rr++)
        uu[rr] = *((const uint4*)(srcb + (size_t)rr * 16 * 16384) + c);
    };
    auto WRITEB = [&](const uint4* uu) {
#pragma unroll
      for (int rr = 0; rr < 4; rr++) {
        int row = r0 + rr * 16;
        float* dst = &ks[row * 132 + c * 8];
        float4 lo, hi;
        lo.x = bflo(uu[rr].x); lo.y = bfhi(uu[rr].x); lo.z = bflo(uu[rr].y); lo.w = bfhi(uu[rr].y);
        hi.x = bflo(uu[rr].z); hi.y = bfhi(uu[rr].z); hi.z = bflo(uu[rr].w); hi.w = bfhi(uu[rr].w);
        *(float4*)dst = lo;
        *(float4*)(dst + 4) = hi;
      }
    };
    uint4 su[4];
    LOADB(0, su); WRITEB(su);
    __syncthreads();
    LOADB(1, su);        // prefetch khalf 1 into regs; hides under COMPUTE(0)
    COMPUTE(0);
    __syncthreads();
    WRITEB(su);
    __syncthreads();
    COMPUTE(1);
  } else {
    const int c = t & 31, r0 = t >> 5;  // 32 float4 per row-half, 8 row-groups
    auto LOADF = [&](int kh2, float4* vv) {
      const float* src = (const float*)keys + ((size_t)(lstart + r0) * 64 + b) * 256 + kh2 * 128 + c * 4;
#pragma unroll
      for (int rr = 0; rr < 8; rr++) vv[rr] = *(const float4*)(src + (size_t)rr * 8 * 16384);
    };
    auto WRITEF = [&](const float4* vv) {
#pragma unroll
      for (int rr = 0; rr < 8; rr++) *(float4*)&ks[(r0 + rr * 8) * 132 + c * 4] = vv[rr];
    };
    float4 sv[8];
    LOADF(0, sv); WRITEF(sv);
    __syncthreads();
    LOADF(1, sv);        // prefetch khalf 1 into regs; hides under COMPUTE(0)
    COMPUTE(0);
    __syncthreads();
    WRITEF(sv);
    __syncthreads();
    COMPUTE(1);
  }

  // reduce over 8-lane k-slice groups; write scores * rpe (per-wave rows -> no race)
  {
    const int rowbase = wave * 16;
#pragma unroll
    for (int r = 0; r < 16; r++) {
      float v = accs[r];
      v += __shfl_xor(v, 1);
      v += __shfl_xor(v, 2);
      v += __shfl_xor(v, 4);
      if (ks8 == 0) w_lds[(rowbase + r) * 12 + h8] = v * rpe_lds[rowbase + r];
    }
  }
  __syncthreads();

  // ================= partial softmax: 32 threads per h over 64 rows ==========
  {
    const int h = t >> 5, j = t & 31;
    float s0 = (j < lcnt) ? w_lds[j * 12 + h] : -3.0e38f;
    float s1 = (j + 32 < lcnt) ? w_lds[(j + 32) * 12 + h] : -3.0e38f;
    float m = fmaxf(s0, s1);
#pragma unroll
    for (int off = 16; off >= 1; off >>= 1) m = fmaxf(m, __shfl_xor(m, off, 32));
    float e0 = (j < lcnt) ? __expf(s0 - m) : 0.f;
    float e1 = (j + 32 < lcnt) ? __expf(s1 - m) : 0.f;
    w_lds[j * 12 + h] = e0;          // dead rows get 0
    w_lds[(j + 32) * 12 + h] = e1;
    float zs = e0 + e1;
#pragma unroll
    for (int off = 16; off >= 1; off >>= 1) zs += __shfl_xor(zs, off, 32);
    if (j == 0) mz_lds[h] = make_float2(m, zs);
  }
  __syncthreads();
  if (t < 8) mz_part[((size_t)chunk * 64 + b) * 8 + t] = mz_lds[t];

  // ================= read phase: O_c[h][v] = sum_l w[l][h]*vals[l][v] ========
  // wave owns v-slice [wave*64, wave*64+64); lane = (rg = lane>>4, vslot = lane&15)
  const int vslot = lane & 15, rg = lane >> 4;
  float acc[8][4];
#pragma unroll
  for (int hh = 0; hh < 8; hh++)
#pragma unroll
    for (int cc = 0; cc < 4; cc++) acc[hh][cc] = 0.f;

  if (bf) {
    const u32* vb = (const u32*)vals + ((size_t)lstart * 64 + b) * 128 + wave * 32 + vslot * 2;
    for (int i0 = 0; i0 < 16; i0 += 8) {
      uint2 uu[8];
#pragma unroll
      for (int jb = 0; jb < 8; jb++) {
        int row = rg + 4 * (i0 + jb);
        uu[jb] = *(const uint2*)(vb + (size_t)row * 8192);
      }
#pragma unroll
      for (int jb = 0; jb < 8; jb++) {
        int row = rg + 4 * (i0 + jb);
        float4 w0 = *(const float4*)&w_lds[row * 12];
        float4 w1 = *(const float4*)&w_lds[row * 12 + 4];
        float v0 = bflo(uu[jb].x), v1 = bfhi(uu[jb].x);
        float v2 = bflo(uu[jb].y), v3 = bfhi(uu[jb].y);
        acc[0][0] += w0.x * v0; acc[0][1] += w0.x * v1; acc[0][2] += w0.x * v2; acc[0][3] += w0.x * v3;
        acc[1][0] += w0.y * v0; acc[1][1] += w0.y * v1; acc[1][2] += w0.y * v2; acc[1][3] += w0.y * v3;
        acc[2][0] += w0.z * v0; acc[2][1] += w0.z * v1; acc[2][2] += w0.z * v2; acc[2][3] += w0.z * v3;
        acc[3][0] += w0.w * v0; acc[3][1] += w0.w * v1; acc[3][2] += w0.w * v2; acc[3][3] += w0.w * v3;
        acc[4][0] += w1.x * v0; acc[4][1] += w1.x * v1; acc[4][2] += w1.x * v2; acc[4][3] += w1.x * v3;
        acc[5][0] += w1.y * v0; acc[5][1] += w1.y * v1; acc[5][2] += w1.y * v2; acc[5][3] += w1.y * v3;
        acc[6][0] += w1.z * v0; acc[6][1] += w1.z * v1; acc[6][2] += w1.z * v2; acc[6][3] += w1.z * v3;
        acc[7][0] += w1.w * v0; acc[7][1] += w1.w * v1; acc[7][2] += w1.w * v2; acc[7][3] += w1.w * v3;
      }
    }
  } else {
    const float* vb = (const float*)vals + ((size_t)lstart * 64 + b) * 256 + wave * 64 + vslot * 4;
    for (int i0 = 0; i0 < 16; i0 += 8) {
      float4 vv[8];
#pragma unroll
      for (int jb = 0; jb < 8; jb++) {
        int row = rg + 4 * (i0 + jb);
        vv[jb] = *(const float4*)(vb + (size_t)row * 16384);
      }
#pragma unroll
      for (int jb = 0; jb < 8; jb++) {
        int row = rg + 4 * (i0 + jb);
        float4 w0 = *(const float4*)&w_lds[row * 12];
        float4 w1 = *(const float4*)&w_lds[row * 12 + 4];
        acc[0][0] += w0.x * vv[jb].x; acc[0][1] += w0.x * vv[jb].y; acc[0][2] += w0.x * vv[jb].z; acc[0][3] += w0.x * vv[jb].w;
        acc[1][0] += w0.y * vv[jb].x; acc[1][1] += w0.y * vv[jb].y; acc[1][2] += w0.y * vv[jb].z; acc[1][3] += w0.y * vv[jb].w;
        acc[2][0] += w0.z * vv[jb].x; acc[2][1] += w0.z * vv[jb].y; acc[2][2] += w0.z * vv[jb].z; acc[2][3] += w0.z * vv[jb].w;
        acc[3][0] += w0.w * vv[jb].x; acc[3][1] += w0.w * vv[jb].y; acc[3][2] += w0.w * vv[jb].z; acc[3][3] += w0.w * vv[jb].w;
        acc[4][0] += w1.x * vv[jb].x; acc[4][1] += w1.x * vv[jb].y; acc[4][2] += w1.x * vv[jb].z; acc[4][3] += w1.x * vv[jb].w;
        acc[5][0] += w1.y * vv[jb].x; acc[5][1] += w1.y * vv[jb].y; acc[5][2] += w1.y * vv[jb].z; acc[5][3] += w1.y * vv[jb].w;
        acc[6][0] += w1.z * vv[jb].x; acc[6][1] += w1.z * vv[jb].y; acc[6][2] += w1.z * vv[jb].z; acc[6][3] += w1.z * vv[jb].w;
        acc[7][0] += w1.w * vv[jb].x; acc[7][1] += w1.w * vv[jb].y; acc[7][2] += w1.w * vv[jb].z; acc[7][3] += w1.w * vv[jb].w;
      }
    }
  }

  // in-wave combine over 4 row-groups, then 16 lanes store the wave's v-slice
#pragma unroll
  for (int hh = 0; hh < 8; hh++)
#pragma unroll
    for (int cc = 0; cc < 4; cc++) {
      float v = acc[hh][cc];
      v += __shfl_xor(v, 16);
      v += __shfl_xor(v, 32);
      acc[hh][cc] = v;
    }
  if (rg == 0) {
    float* op = O_part + ((size_t)chunk * 64 + b) * 2048 + wave * 64 + vslot * 4;
#pragma unroll
    for (int hh = 0; hh < 8; hh++) {
      float4 o = make_float4(acc[hh][0], acc[hh][1], acc[hh][2], acc[hh][3]);
      *(float4*)&op[hh * 256] = o;
    }
  }
}

// ---------------------------------------------------------------------------
// k_out1: per (h,b): combine 32 chunk partials -> rn[256]; out_part = rn @ Wa
// grid (8 h, 64 b), block 256 (one output column each). Batched loads.
__global__ __launch_bounds__(256) void k_out1(const void* keys, const void* Wa,
                                              const int* steps, const float* O_part,
                                              const float2* mz_part, float* out_part) {
  const int h = blockIdx.x, b = blockIdx.y;
  const bool bf = sniff_bf16(keys);
  const int t = threadIdx.x;  // 0..255 = output column
  const int nlive = (steps[b] + CH - 1) >> 6;  // 1..32

  // chunk scale factors (uniform scalar work, all threads redundant)
  float2 mzv[NCH];
#pragma unroll
  for (int c = 0; c < NCH; c++)
    mzv[c] = (c < nlive) ? mz_part[((size_t)c * 64 + b) * 8 + h] : make_float2(-3.0e38f, 0.f);
  float M = -3.0e38f;
#pragma unroll
  for (int c = 0; c < NCH; c++) M = fmaxf(M, mzv[c].x);
  float sc[NCH];
  float Z = 0.f;
#pragma unroll
  for (int c = 0; c < NCH; c++) {
    sc[c] = __expf(mzv[c].x - M);
    Z += sc[c] * mzv[c].y;
  }
  const float zi = 1.0f / Z;

  // combine O_part chunks (two batches of 16 independent loads)
  __shared__ float rn[256];
  {
    const float* op = O_part + (size_t)b * 2048 + h * 256 + t;
    float s = 0.f;
    float ov[16];
#pragma unroll
    for (int c = 0; c < 16; c++) ov[c] = (c < nlive) ? op[(size_t)c * 131072] : 0.f;
#pragma unroll
    for (int c = 0; c < 16; c++) s += sc[c] * ov[c];
#pragma unroll
    for (int c = 0; c < 16; c++) ov[c] = (c + 16 < nlive) ? op[(size_t)(c + 16) * 131072] : 0.f;
#pragma unroll
    for (int c = 0; c < 16; c++) s += sc[c + 16] * ov[c];
    rn[t] = s * zi;
  }
  __syncthreads();

  float a = 0.f;
  if (bf) {
    const u32* wa = (const u32*)Wa + (size_t)(h * 256) * 128 + (t >> 1);
    const bool hi = (t & 1);
    for (int c0 = 0; c0 < 256; c0 += 16) {
      u32 wv[16];
#pragma unroll
      for (int j = 0; j < 16; j++) wv[j] = wa[(size_t)(c0 + j) * 128];
#pragma unroll
      for (int j = 0; j < 16; j++)
        a += rn[c0 + j] * (hi ? bfhi(wv[j]) : bflo(wv[j]));
    }
  } else {
    const float* wa = (const float*)Wa + (size_t)(h * 256) * 256 + t;
    for (int c0 = 0; c0 < 256; c0 += 16) {
      float wv[16];
#pragma unroll
      for (int j = 0; j < 16; j++) wv[j] = wa[(size_t)(c0 + j) * 256];
#pragma unroll
      for (int j = 0; j < 16; j++) a += rn[c0 + j] * wv[j];
    }
  }
  out_part[(size_t)(h * 64 + b) * 256 + t] = a;
}

// ---------------------------------------------------------------------------
// k_out2: out[b,v] = sum_h out_part[h][b][v] + ba[v]   (dtype by sniff)
// grid 64, block 256
__global__ __launch_bounds__(256) void k_out2(const void* keys, const void* ba,
                                              const float* out_part, void* out) {
  const int b = blockIdx.x, t = threadIdx.x;
  const bool bf = sniff_bf16(keys);
  float s = bf ? bf1(((const u16*)ba)[t]) : ((const float*)ba)[t];
  float ov[8];
#pragma unroll
  for (int h = 0; h < 8; h++) ov[h] = out_part[(size_t)(h * 64 + b) * 256 + t];
#pragma unroll
  for (int h = 0; h < 8; h++) s += ov[h];
  if (bf)
    ((__hip_bfloat16*)out)[b * 256 + t] = __float2bfloat16(s);
  else
    ((float*)out)[b * 256 + t] = s;
}

// ---------------------------------------------------------------------------
extern "C" void kernel_launch(void* const* d_in, const int* in_sizes, int n_in,
                              void* d_out, int out_size, void* d_ws, size_t ws_size,
                              hipStream_t stream) {
  (void)in_sizes; (void)n_in; (void)out_size; (void)ws_size;
  const void* query = d_in[0];
  const void* keys = d_in[1];
  const void* vals = d_in[2];
  const void* rpe = d_in[3];
  const void* Wq = d_in[4];
  const void* bq = d_in[5];
  const void* Wa = d_in[6];
  const void* ba = d_in[7];
  const int* steps = (const int*)d_in[8];

  float* ws = (float*)d_ws;
  float* q_ws = ws;                                  // 131072 f
  float* O_part = ws + 131072;                       // 4194304 f (32 chunks x 64 b x 2048)
  float2* mz_part = (float2*)(ws + 131072 + 4194304);  // 32768 f
  float* out_part = ws + 131072 + 4194304 + 32768;   // 131072 f  (total ~18 MB)

  k_prep<<<dim3(4, 64), 256, 0, stream>>>(keys, query, Wq, bq, q_ws);
  k_fused<<<dim3(NCH, 64), 256, 0, stream>>>(keys, vals, rpe, steps, q_ws, O_part, mz_part);
  k_out1<<<dim3(8, 64), 256, 0, stream>>>(keys, Wa, steps, O_part, mz_part, out_part);
  k_out2<<<64, 256, 0, stream>>>(keys, ba, out_part, d_out);
}

// Round 4
// 304.782 us; speedup vs baseline: 1.7869x; 1.0457x over previous
//
#include <hip/hip_runtime.h>
#include <hip/hip_bf16.h>
#include <cstdint>

// Problem constants
#define Ln 2048
#define Bn 64
#define Kd 256
#define Vd 256
#define Hn 8

#define CH 64    // l-rows per fused chunk
#define NCH 32   // number of chunks (Ln / CH)

using u32 = unsigned int;
using u16 = unsigned short;

__device__ __forceinline__ float bflo(u32 u) { return __uint_as_float(u << 16); }
__device__ __forceinline__ float bfhi(u32 u) { return __uint_as_float(u & 0xffff0000u); }
__device__ __forceinline__ float bf1(u16 s) { return __uint_as_float(((u32)s) << 16); }

// Device-side dtype sniff on `keys` (little-endian aware): u16[2i] is the LOW
// mantissa half of float[i] for fp32 data -> ~14% sane-bf16; for genuine bf16
// data it's a real N(0,1) value -> ~100% sane. (Rounds 1-3 verified: fp32.)
__device__ __forceinline__ bool sniff_bf16(const void* keys) {
  const u16* q = (const u16*)keys;
  int lane = threadIdx.x & 63;
  u16 u = q[2 * (lane * 127)];
  u32 e = (u >> 7) & 0xff;
  bool sane = (u == 0) || (e >= 100 && e <= 134);
  return __popcll(__ballot(sane)) > 32;
}

// ---------------------------------------------------------------------------
// k_prep: q = query @ Wq + bq  (fp32 in ws)   grid (4 chunks, 64 b), block 256
__global__ __launch_bounds__(256) void k_prep(const void* keys, const void* query,
                                              const void* Wq, const void* bq,
                                              float* q_ws) {
  const bool bf = sniff_bf16(keys);
  const int t = threadIdx.x;
  const int chunk = blockIdx.x;  // 0..3
  const int b = blockIdx.y;      // 0..63

  __shared__ float ql[256];
  ql[t] = bf ? bf1(((const u16*)query)[b * 256 + t]) : ((const float*)query)[b * 256 + t];
  __syncthreads();

  int c0 = chunk * 512 + 2 * t;  // two output columns per thread
  float a0, a1;
  if (bf) { a0 = bf1(((const u16*)bq)[c0]); a1 = bf1(((const u16*)bq)[c0 + 1]); }
  else    { a0 = ((const float*)bq)[c0];    a1 = ((const float*)bq)[c0 + 1]; }

  if (bf) {
    const u32* w = (const u32*)Wq + chunk * 256 + t;
    for (int k0 = 0; k0 < 256; k0 += 16) {
      u32 wv[16];
#pragma unroll
      for (int j = 0; j < 16; j++) wv[j] = w[(size_t)(k0 + j) * 1024];
#pragma unroll
      for (int j = 0; j < 16; j++) {
        float qk = ql[k0 + j];
        a0 += qk * bflo(wv[j]); a1 += qk * bfhi(wv[j]);
      }
    }
  } else {
    const float2* w = (const float2*)Wq + chunk * 256 + t;
    for (int k0 = 0; k0 < 256; k0 += 16) {
      float2 wv[16];
#pragma unroll
      for (int j = 0; j < 16; j++) wv[j] = w[(size_t)(k0 + j) * 1024];
#pragma unroll
      for (int j = 0; j < 16; j++) {
        float qk = ql[k0 + j];
        a0 += qk * wv[j].x; a1 += qk * wv[j].y;
      }
    }
  }
  q_ws[b * 2048 + c0] = a0;
  q_ws[b * 2048 + c0 + 1] = a1;
}

// ---------------------------------------------------------------------------
// k_fused: per (chunk of 64 l, b): scores with q in 4 NAMED float4 regs per
// k-half (lane=(h,kslice)), keys via LDS broadcast, 8-lane shuffle reduce;
// partial softmax; weighted vals sum with in-wave combine. grid (32, 64).
// SPILL HISTORY: rounds 1-3 (VGPR 64-68, 40-70 MB scratch writes) used
// lambdas taking local-array pointers + a long-lived qreg[8] array indexed
// through a lambda param -> arrays demoted to scratch (rule #20 variant).
// This version: NO lambdas, NO address-taken register arrays, staging via
// named registers; accs[16] only indexed by unrolled induction vars.
__global__ __launch_bounds__(256) void k_fused(const void* keys, const void* vals,
                                               const void* rpe, const int* steps,
                                               const float* q_ws, float* O_part,
                                               float2* mz_part) {
  const int b = blockIdx.y, chunk = blockIdx.x;
  const int lstart = chunk * CH;
  const int stepb = steps[b];
  if (lstart >= stepb) return;  // dead chunk
  const int lcnt = min(CH, stepb - lstart);
  const bool bf = sniff_bf16(keys);
  const int t = threadIdx.x;
  const int lane = t & 63;
  const int wave = __builtin_amdgcn_readfirstlane(t >> 6);  // 0..3

  __shared__ __align__(16) float ks[CH * 132];   // 33.8 KB (one 128-k half)
  __shared__ __align__(16) float w_lds[CH * 12]; // scores -> weights
  __shared__ float rpe_lds[CH];
  __shared__ float2 mz_lds[8];

  // rpe staging (one dword per row; L2-shared across b)
  if (t < CH) {
    int l = lstart + t;
    rpe_lds[t] = bf ? bf1(((const u16*)rpe)[l * 64 + b]) : ((const float*)rpe)[l * 64 + b];
  }

  const int h8 = lane >> 3, ks8 = lane & 7;
  const float* qb2 = q_ws + b * 2048 + h8 * 256 + ks8 * 4;

  // ================= score phase =================
  float accs[16];
#pragma unroll
  for (int r = 0; r < 16; r++) accs[r] = 0.f;

// stage keys k-half KH (0/1) into ks via NAMED registers (fp32 path)
#define STAGE_F(KH) do {                                                      \
    const float* kb = (const float*)keys +                                    \
        ((size_t)(lstart + r0f) * 64 + b) * 256 + (KH) * 128 + cf * 4;        \
    float4 s0 = *(const float4*)(kb + 0 * 131072);                            \
    float4 s1 = *(const float4*)(kb + 1 * 131072);                            \
    float4 s2 = *(const float4*)(kb + 2 * 131072);                            \
    float4 s3 = *(const float4*)(kb + 3 * 131072);                            \
    float4 s4 = *(const float4*)(kb + 4 * 131072);                            \
    float4 s5 = *(const float4*)(kb + 5 * 131072);                            \
    float4 s6 = *(const float4*)(kb + 6 * 131072);                            \
    float4 s7 = *(const float4*)(kb + 7 * 131072);                            \
    *(float4*)&ks[(r0f + 0 * 8) * 132 + cf * 4] = s0;                         \
    *(float4*)&ks[(r0f + 1 * 8) * 132 + cf * 4] = s1;                         \
    *(float4*)&ks[(r0f + 2 * 8) * 132 + cf * 4] = s2;                         \
    *(float4*)&ks[(r0f + 3 * 8) * 132 + cf * 4] = s3;                         \
    *(float4*)&ks[(r0f + 4 * 8) * 132 + cf * 4] = s4;                         \
    *(float4*)&ks[(r0f + 5 * 8) * 132 + cf * 4] = s5;                         \
    *(float4*)&ks[(r0f + 6 * 8) * 132 + cf * 4] = s6;                         \
    *(float4*)&ks[(r0f + 7 * 8) * 132 + cf * 4] = s7;                         \
  } while (0)

// stage keys k-half KH into ks, bf16 path (4 named uint4 -> 8 float4)
#define STAGE_B(KH) do {                                                      \
    const u16* kb = (const u16*)keys +                                        \
        ((size_t)(lstart + r0B) * 64 + b) * 256 + (KH) * 128 + cB * 8;        \
    uint4 u0 = *(const uint4*)(kb + 0 * 262144);                              \
    uint4 u1 = *(const uint4*)(kb + 1 * 262144);                              \
    uint4 u2 = *(const uint4*)(kb + 2 * 262144);                              \
    uint4 u3 = *(const uint4*)(kb + 3 * 262144);                              \
    float* d0 = &ks[(r0B + 0 * 16) * 132 + cB * 8];                           \
    float* d1 = &ks[(r0B + 1 * 16) * 132 + cB * 8];                           \
    float* d2 = &ks[(r0B + 2 * 16) * 132 + cB * 8];                           \
    float* d3 = &ks[(r0B + 3 * 16) * 132 + cB * 8];                           \
    *(float4*)d0 = make_float4(bflo(u0.x), bfhi(u0.x), bflo(u0.y), bfhi(u0.y)); \
    *(float4*)(d0 + 4) = make_float4(bflo(u0.z), bfhi(u0.z), bflo(u0.w), bfhi(u0.w)); \
    *(float4*)d1 = make_float4(bflo(u1.x), bfhi(u1.x), bflo(u1.y), bfhi(u1.y)); \
    *(float4*)(d1 + 4) = make_float4(bflo(u1.z), bfhi(u1.z), bflo(u1.w), bfhi(u1.w)); \
    *(float4*)d2 = make_float4(bflo(u2.x), bfhi(u2.x), bflo(u2.y), bfhi(u2.y)); \
    *(float4*)(d2 + 4) = make_float4(bflo(u2.z), bfhi(u2.z), bflo(u2.w), bfhi(u2.w)); \
    *(float4*)d3 = make_float4(bflo(u3.x), bfhi(u3.x), bflo(u3.y), bfhi(u3.y)); \
    *(float4*)(d3 + 4) = make_float4(bflo(u3.z), bfhi(u3.z), bflo(u3.w), bfhi(u3.w)); \
  } while (0)

// compute 16 rows against the staged half using 4 named q regs
#define SCORE_COMPUTE(QA, QB, QC, QD) do {                                    \
    _Pragma("unroll")                                                         \
    for (int r = 0; r < 16; r++) {                                            \
      const float* kp = &ks[(wave * 16 + r) * 132 + ks8 * 4];                 \
      float4 k0 = *(const float4*)kp;                                         \
      float4 k1 = *(const float4*)(kp + 32);                                  \
      float4 k2 = *(const float4*)(kp + 64);                                  \
      float4 k3 = *(const float4*)(kp + 96);                                  \
      float a = accs[r];                                                      \
      a += k0.x * QA.x + k0.y * QA.y + k0.z * QA.z + k0.w * QA.w;             \
      a += k1.x * QB.x + k1.y * QB.y + k1.z * QB.z + k1.w * QB.w;             \
      a += k2.x * QC.x + k2.y * QC.y + k2.z * QC.z + k2.w * QC.w;             \
      a += k3.x * QD.x + k3.y * QD.y + k3.z * QD.z + k3.w * QD.w;             \
      accs[r] = a;                                                            \
    }                                                                         \
  } while (0)

  if (bf) {
    const int cB = t & 15, r0B = t >> 4;  // 16 uint4 per row-half, 16 row-groups
    STAGE_B(0);
    __syncthreads();
    {
      float4 qA = *(const float4*)&qb2[0];
      float4 qB = *(const float4*)&qb2[32];
      float4 qC = *(const float4*)&qb2[64];
      float4 qD = *(const float4*)&qb2[96];
      SCORE_COMPUTE(qA, qB, qC, qD);
    }
    __syncthreads();
    STAGE_B(1);
    __syncthreads();
    {
      float4 qA = *(const float4*)&qb2[128];
      float4 qB = *(const float4*)&qb2[160];
      float4 qC = *(const float4*)&qb2[192];
      float4 qD = *(const float4*)&qb2[224];
      SCORE_COMPUTE(qA, qB, qC, qD);
    }
  } else {
    const int cf = t & 31, r0f = t >> 5;  // 32 float4 per row-half, 8 row-groups
    STAGE_F(0);
    __syncthreads();
    {
      float4 qA = *(const float4*)&qb2[0];
      float4 qB = *(const float4*)&qb2[32];
      float4 qC = *(const float4*)&qb2[64];
      float4 qD = *(const float4*)&qb2[96];
      SCORE_COMPUTE(qA, qB, qC, qD);
    }
    __syncthreads();
    STAGE_F(1);
    __syncthreads();
    {
      float4 qA = *(const float4*)&qb2[128];
      float4 qB = *(const float4*)&qb2[160];
      float4 qC = *(const float4*)&qb2[192];
      float4 qD = *(const float4*)&qb2[224];
      SCORE_COMPUTE(qA, qB, qC, qD);
    }
  }

  // reduce over 8-lane k-slice groups; write scores * rpe (per-wave rows -> no race)
  {
#pragma unroll
    for (int r = 0; r < 16; r++) {
      float v = accs[r];
      v += __shfl_xor(v, 1);
      v += __shfl_xor(v, 2);
      v += __shfl_xor(v, 4);
      if (ks8 == 0) w_lds[(wave * 16 + r) * 12 + h8] = v * rpe_lds[wave * 16 + r];
    }
  }
  __syncthreads();

  // ================= partial softmax: 32 threads per h over 64 rows ==========
  {
    const int h = t >> 5, j = t & 31;
    float s0 = (j < lcnt) ? w_lds[j * 12 + h] : -3.0e38f;
    float s1 = (j + 32 < lcnt) ? w_lds[(j + 32) * 12 + h] : -3.0e38f;
    float m = fmaxf(s0, s1);
#pragma unroll
    for (int off = 16; off >= 1; off >>= 1) m = fmaxf(m, __shfl_xor(m, off, 32));
    float e0 = (j < lcnt) ? __expf(s0 - m) : 0.f;
    float e1 = (j + 32 < lcnt) ? __expf(s1 - m) : 0.f;
    w_lds[j * 12 + h] = e0;          // dead rows get 0
    w_lds[(j + 32) * 12 + h] = e1;
    float zs = e0 + e1;
#pragma unroll
    for (int off = 16; off >= 1; off >>= 1) zs += __shfl_xor(zs, off, 32);
    if (j == 0) mz_lds[h] = make_float2(m, zs);
  }
  __syncthreads();
  if (t < 8) mz_part[((size_t)chunk * 64 + b) * 8 + t] = mz_lds[t];

  // ================= read phase: O_c[h][v] = sum_l w[l][h]*vals[l][v] ========
  // wave owns v-slice [wave*64, wave*64+64); lane = (rg = lane>>4, vslot = lane&15)
  const int vslot = lane & 15, rg = lane >> 4;
  float acc[8][4];
#pragma unroll
  for (int hh = 0; hh < 8; hh++)
#pragma unroll
    for (int cc = 0; cc < 4; cc++) acc[hh][cc] = 0.f;

  if (bf) {
    const u32* vb = (const u32*)vals + ((size_t)lstart * 64 + b) * 128 + wave * 32 + vslot * 2;
    for (int i0 = 0; i0 < 16; i0 += 8) {
      uint2 uu[8];
#pragma unroll
      for (int jb = 0; jb < 8; jb++) {
        int row = rg + 4 * (i0 + jb);
        uu[jb] = *(const uint2*)(vb + (size_t)row * 8192);
      }
#pragma unroll
      for (int jb = 0; jb < 8; jb++) {
        int row = rg + 4 * (i0 + jb);
        float4 w0 = *(const float4*)&w_lds[row * 12];
        float4 w1 = *(const float4*)&w_lds[row * 12 + 4];
        float v0 = bflo(uu[jb].x), v1 = bfhi(uu[jb].x);
        float v2 = bflo(uu[jb].y), v3 = bfhi(uu[jb].y);
        acc[0][0] += w0.x * v0; acc[0][1] += w0.x * v1; acc[0][2] += w0.x * v2; acc[0][3] += w0.x * v3;
        acc[1][0] += w0.y * v0; acc[1][1] += w0.y * v1; acc[1][2] += w0.y * v2; acc[1][3] += w0.y * v3;
        acc[2][0] += w0.z * v0; acc[2][1] += w0.z * v1; acc[2][2] += w0.z * v2; acc[2][3] += w0.z * v3;
        acc[3][0] += w0.w * v0; acc[3][1] += w0.w * v1; acc[3][2] += w0.w * v2; acc[3][3] += w0.w * v3;
        acc[4][0] += w1.x * v0; acc[4][1] += w1.x * v1; acc[4][2] += w1.x * v2; acc[4][3] += w1.x * v3;
        acc[5][0] += w1.y * v0; acc[5][1] += w1.y * v1; acc[5][2] += w1.y * v2; acc[5][3] += w1.y * v3;
        acc[6][0] += w1.z * v0; acc[6][1] += w1.z * v1; acc[6][2] += w1.z * v2; acc[6][3] += w1.z * v3;
        acc[7][0] += w1.w * v0; acc[7][1] += w1.w * v1; acc[7][2] += w1.w * v2; acc[7][3] += w1.w * v3;
      }
    }
  } else {
    const float* vb = (const float*)vals + ((size_t)lstart * 64 + b) * 256 + wave * 64 + vslot * 4;
    for (int i0 = 0; i0 < 16; i0 += 8) {
      float4 vv[8];
#pragma unroll
      for (int jb = 0; jb < 8; jb++) {
        int row = rg + 4 * (i0 + jb);
        vv[jb] = *(const float4*)(vb + (size_t)row * 16384);
      }
#pragma unroll
      for (int jb = 0; jb < 8; jb++) {
        int row = rg + 4 * (i0 + jb);
        float4 w0 = *(const float4*)&w_lds[row * 12];
        float4 w1 = *(const float4*)&w_lds[row * 12 + 4];
        acc[0][0] += w0.x * vv[jb].x; acc[0][1] += w0.x * vv[jb].y; acc[0][2] += w0.x * vv[jb].z; acc[0][3] += w0.x * vv[jb].w;
        acc[1][0] += w0.y * vv[jb].x; acc[1][1] += w0.y * vv[jb].y; acc[1][2] += w0.y * vv[jb].z; acc[1][3] += w0.y * vv[jb].w;
        acc[2][0] += w0.z * vv[jb].x; acc[2][1] += w0.z * vv[jb].y; acc[2][2] += w0.z * vv[jb].z; acc[2][3] += w0.z * vv[jb].w;
        acc[3][0] += w0.w * vv[jb].x; acc[3][1] += w0.w * vv[jb].y; acc[3][2] += w0.w * vv[jb].z; acc[3][3] += w0.w * vv[jb].w;
        acc[4][0] += w1.x * vv[jb].x; acc[4][1] += w1.x * vv[jb].y; acc[4][2] += w1.x * vv[jb].z; acc[4][3] += w1.x * vv[jb].w;
        acc[5][0] += w1.y * vv[jb].x; acc[5][1] += w1.y * vv[jb].y; acc[5][2] += w1.y * vv[jb].z; acc[5][3] += w1.y * vv[jb].w;
        acc[6][0] += w1.z * vv[jb].x; acc[6][1] += w1.z * vv[jb].y; acc[6][2] += w1.z * vv[jb].z; acc[6][3] += w1.z * vv[jb].w;
        acc[7][0] += w1.w * vv[jb].x; acc[7][1] += w1.w * vv[jb].y; acc[7][2] += w1.w * vv[jb].z; acc[7][3] += w1.w * vv[jb].w;
      }
    }
  }

  // in-wave combine over 4 row-groups, then 16 lanes store the wave's v-slice
#pragma unroll
  for (int hh = 0; hh < 8; hh++)
#pragma unroll
    for (int cc = 0; cc < 4; cc++) {
      float v = acc[hh][cc];
      v += __shfl_xor(v, 16);
      v += __shfl_xor(v, 32);
      acc[hh][cc] = v;
    }
  if (rg == 0) {
    float* op = O_part + ((size_t)chunk * 64 + b) * 2048 + wave * 64 + vslot * 4;
#pragma unroll
    for (int hh = 0; hh < 8; hh++) {
      float4 o = make_float4(acc[hh][0], acc[hh][1], acc[hh][2], acc[hh][3]);
      *(float4*)&op[hh * 256] = o;
    }
  }
}

// ---------------------------------------------------------------------------
// k_out1: per (h,b): combine 32 chunk partials -> rn[256]; out_part = rn @ Wa
// grid (8 h, 64 b), block 256 (one output column each). Batched loads.
__global__ __launch_bounds__(256) void k_out1(const void* keys, const void* Wa,
                                              const int* steps, const float* O_part,
                                              const float2* mz_part, float* out_part) {
  const int h = blockIdx.x, b = blockIdx.y;
  const bool bf = sniff_bf16(keys);
  const int t = threadIdx.x;  // 0..255 = output column
  const int nlive = (steps[b] + CH - 1) >> 6;  // 1..32

  // chunk scale factors (uniform scalar work, all threads redundant)
  float2 mzv[NCH];
#pragma unroll
  for (int c = 0; c < NCH; c++)
    mzv[c] = (c < nlive) ? mz_part[((size_t)c * 64 + b) * 8 + h] : make_float2(-3.0e38f, 0.f);
  float M = -3.0e38f;
#pragma unroll
  for (int c = 0; c < NCH; c++) M = fmaxf(M, mzv[c].x);
  float sc[NCH];
  float Z = 0.f;
#pragma unroll
  for (int c = 0; c < NCH; c++) {
    sc[c] = __expf(mzv[c].x - M);
    Z += sc[c] * mzv[c].y;
  }
  const float zi = 1.0f / Z;

  // combine O_part chunks (two batches of 16 independent loads)
  __shared__ float rn[256];
  {
    const float* op = O_part + (size_t)b * 2048 + h * 256 + t;
    float s = 0.f;
    float ov[16];
#pragma unroll
    for (int c = 0; c < 16; c++) ov[c] = (c < nlive) ? op[(size_t)c * 131072] : 0.f;
#pragma unroll
    for (int c = 0; c < 16; c++) s += sc[c] * ov[c];
#pragma unroll
    for (int c = 0; c < 16; c++) ov[c] = (c + 16 < nlive) ? op[(size_t)(c + 16) * 131072] : 0.f;
#pragma unroll
    for (int c = 0; c < 16; c++) s += sc[c + 16] * ov[c];
    rn[t] = s * zi;
  }
  __syncthreads();

  float a = 0.f;
  if (bf) {
    const u32* wa = (const u32*)Wa + (size_t)(h * 256) * 128 + (t >> 1);
    const bool hi = (t & 1);
    for (int c0 = 0; c0 < 256; c0 += 16) {
      u32 wv[16];
#pragma unroll
      for (int j = 0; j < 16; j++) wv[j] = wa[(size_t)(c0 + j) * 128];
#pragma unroll
      for (int j = 0; j < 16; j++)
        a += rn[c0 + j] * (hi ? bfhi(wv[j]) : bflo(wv[j]));
    }
  } else {
    const float* wa = (const float*)Wa + (size_t)(h * 256) * 256 + t;
    for (int c0 = 0; c0 < 256; c0 += 16) {
      float wv[16];
#pragma unroll
      for (int j = 0; j < 16; j++) wv[j] = wa[(size_t)(c0 + j) * 256];
#pragma unroll
      for (int j = 0; j < 16; j++) a += rn[c0 + j] * wv[j];
    }
  }
  out_part[(size_t)(h * 64 + b) * 256 + t] = a;
}

// ---------------------------------------------------------------------------
// k_out2: out[b,v] = sum_h out_part[h][b][v] + ba[v]   (dtype by sniff)
// grid 64, block 256
__global__ __launch_bounds__(256) void k_out2(const void* keys, const void* ba,
                                              const float* out_part, void* out) {
  const int b = blockIdx.x, t = threadIdx.x;
  const bool bf = sniff_bf16(keys);
  float s = bf ? bf1(((const u16*)ba)[t]) : ((const float*)ba)[t];
  float ov[8];
#pragma unroll
  for (int h = 0; h < 8; h++) ov[h] = out_part[(size_t)(h * 64 + b) * 256 + t];
#pragma unroll
  for (int h = 0; h < 8; h++) s += ov[h];
  if (bf)
    ((__hip_bfloat16*)out)[b * 256 + t] = __float2bfloat16(s);
  else
    ((float*)out)[b * 256 + t] = s;
}

// ---------------------------------------------------------------------------
extern "C" void kernel_launch(void* const* d_in, const int* in_sizes, int n_in,
                              void* d_out, int out_size, void* d_ws, size_t ws_size,
                              hipStream_t stream) {
  (void)in_sizes; (void)n_in; (void)out_size; (void)ws_size;
  const void* query = d_in[0];
  const void* keys = d_in[1];
  const void* vals = d_in[2];
  const void* rpe = d_in[3];
  const void* Wq = d_in[4];
  const void* bq = d_in[5];
  const void* Wa = d_in[6];
  const void* ba = d_in[7];
  const int* steps = (const int*)d_in[8];

  float* ws = (float*)d_ws;
  float* q_ws = ws;                                  // 131072 f
  float* O_part = ws + 131072;                       // 4194304 f (32 chunks x 64 b x 2048)
  float2* mz_part = (float2*)(ws + 131072 + 4194304);  // 32768 f
  float* out_part = ws + 131072 + 4194304 + 32768;   // 131072 f  (total ~18 MB)

  k_prep<<<dim3(4, 64), 256, 0, stream>>>(keys, query, Wq, bq, q_ws);
  k_fused<<<dim3(NCH, 64), 256, 0, stream>>>(keys, vals, rpe, steps, q_ws, O_part, mz_part);
  k_out1<<<dim3(8, 64), 256, 0, stream>>>(keys, Wa, steps, O_part, mz_part, out_part);
  k_out2<<<64, 256, 0, stream>>>(keys, ba, out_part, d_out);
}